// Round 2
// baseline (293.412 us; speedup 1.0000x reference)
//
#include <hip/hip_runtime.h>

#define Bn    256
#define Cc    7
#define Nn    16384
#define HIDW  256
#define SEL   3
#define Mrows (Bn * Cc)            // 1792
#define KSPLIT 16
#define KCHUNK (Nn / KSPLIT)       // 1024
#define BK    32
#define NIT   (KCHUNK / BK)        // 32 k-steps per block
#define PART_STRIDE ((size_t)Mrows * HIDW)

typedef __attribute__((ext_vector_type(8))) short bf16x8;
typedef __attribute__((ext_vector_type(4))) float floatx4;
typedef __attribute__((ext_vector_type(4))) unsigned int uint32x4;

#if __has_builtin(__builtin_amdgcn_global_load_lds)
#define HAS_GLDS 1
#endif

#if __has_builtin(__builtin_amdgcn_sched_barrier)
#define SCHED_FENCE() __builtin_amdgcn_sched_barrier(0)
#else
#define SCHED_FENCE()
#endif

#ifdef HAS_GLDS
// Counted barrier: only the 4 global_load_lds (issued FIRST in the step, pinned
// by SCHED_FENCE) must land before waves cross; the 4 younger A-prefetch loads
// stay in flight. This avoids the full vmcnt(0) drain __syncthreads() emits.
#define TILE_BARRIER() do { \
    asm volatile("s_waitcnt vmcnt(4)" ::: "memory"); \
    __builtin_amdgcn_s_barrier(); \
    SCHED_FENCE(); \
} while (0)
#define GLDS16(src, dst) __builtin_amdgcn_global_load_lds( \
    (const __attribute__((address_space(1))) void*)(src), \
    (__attribute__((address_space(3))) void*)(dst), 16, 0, 0)
#else
#define TILE_BARRIER() __syncthreads()
#endif

// pack high-16 bits of two fp32 words: low ushort = ua>>16, high = ub>>16
__device__ __forceinline__ unsigned pack_hi16(unsigned ua, unsigned ub) {
#if __has_builtin(__builtin_amdgcn_perm)
    return __builtin_amdgcn_perm(ub, ua, 0x07060302u);
#else
    return (ua >> 16) | (ub & 0xffff0000u);
#endif
}

// truncation hi/lo split of a pair of floats -> packed hi word + packed lo word
__device__ __forceinline__ void split2(float a, float b, unsigned& hp, unsigned& lp) {
    unsigned ua = __float_as_uint(a), ub = __float_as_uint(b);
    float fa = __uint_as_float(ua & 0xffff0000u);
    float fb = __uint_as_float(ub & 0xffff0000u);
    float la = a - fa, lb = b - fb;            // exact residuals
    hp = pack_hi16(ua, ub);
    lp = pack_hi16(__float_as_uint(la), __float_as_uint(lb));
}

__device__ __forceinline__ bf16x8 mk_bf16x8(unsigned a, unsigned b, unsigned c, unsigned d) {
    uint32x4 u = {a, b, c, d};
    return __builtin_bit_cast(bf16x8, u);
}

// 8 consecutive-k fp32 values (two float4) -> bf16 hi and lo fragments
__device__ __forceinline__ void split_frag(const float4& x, const float4& y,
                                           bf16x8& hi, bf16x8& lo) {
    unsigned h0, h1, h2, h3, l0, l1, l2, l3;
    split2(x.x, x.y, h0, l0);
    split2(x.z, x.w, h1, l1);
    split2(y.x, y.y, h2, l2);
    split2(y.z, y.w, h3, l3);
    hi = mk_bf16x8(h0, h1, h2, h3);
    lo = mk_bf16x8(l0, l1, l2, l3);
}

// ---------------------------------------------------------------------------
// K0: w1[k][n] fp32 -> fragment-ordered bf16 hi/lo planes (trunc split).
// chunk(c,T,lane) holds B[k=c*32+(lane>>4)*8+j][n=T*16+(lane&15)], j=0..7,
// at ushort offset ((c*16+T)*64+lane)*8.   (unchanged)
// ---------------------------------------------------------------------------
__global__ __launch_bounds__(256) void convert_w1(const float* __restrict__ w1,
                                                  unsigned short* __restrict__ bhi,
                                                  unsigned short* __restrict__ blo) {
    const int id = blockIdx.x * 256 + threadIdx.x;
    const int l  = id & 63;
    const int ct = id >> 6;
    const int T  = ct & 15;
    const int c  = ct >> 4;
    const int n  = T * 16 + (l & 15);
    const int k  = c * 32 + (l >> 4) * 8;
    float f[8];
#pragma unroll
    for (int j = 0; j < 8; ++j) f[j] = w1[(size_t)(k + j) * HIDW + n];
    unsigned hp[4], lp[4];
#pragma unroll
    for (int m = 0; m < 4; ++m) split2(f[2 * m], f[2 * m + 1], hp[m], lp[m]);
    *(uint4*)(bhi + (size_t)id * 8) = make_uint4(hp[0], hp[1], hp[2], hp[3]);
    *(uint4*)(blo + (size_t)id * 8) = make_uint4(lp[0], lp[1], lp[2], lp[3]);
}

// ---------------------------------------------------------------------------
// K1: MFMA GEMM  part[s][M][256] = feat[M][Kslice] @ w1[Kslice][256]
//   64x128 tile, 4 waves 2x2 (wave tile 32x64), 16x16x32 bf16, 3-pass split.
//   A: direct global->register fragments (lane l: rows base+(l&15), k=(l>>4)*8)
//      -- fully coalesced (lanes r,r+16,r+32,r+48 cover one row's 128B), no LDS.
//   B: global_load_lds into double-buffered LDS, one counted barrier per step.
//   Grid 896 blocks (vs 448 before) -> ~3.5 blocks/CU for latency hiding.
// ---------------------------------------------------------------------------
__global__ __launch_bounds__(256) void gemm_mfma(const float* __restrict__ A,
                                                 const unsigned short* __restrict__ Bhi,
                                                 const unsigned short* __restrict__ Blo,
                                                 float* __restrict__ part) {
    __shared__ unsigned short Bh[8192], Bl[8192];   // 2 buffers x 4096 ushorts each

    // Bijective XCD swizzle over 896 = 8*112 blocks, decoded so runs of 28
    // consecutive blocks share (bx, s): each XCD's L2 keeps its B k-slices hot.
    const int wg  = blockIdx.x;
    const int swz = (wg & 7) * 112 + (wg >> 3);
    const int y     = swz % 28;          // m-tile
    const int combo = swz / 28;          // 0..31
    const int bx = combo >> 4;           // n-tile (0..1)
    const int s  = combo & 15;           // k-slice

    const int m0 = y * 64;
    const int c0 = s * (KCHUNK / 32);    // first 32-wide k-chunk of this slice
    const int t    = threadIdx.x;
    const int lane = t & 63;
    const int w    = t >> 6;
    const int wm   = w & 1;
    const int wn   = w >> 1;

    // A fragment pointers: lane l covers row (m0 + wm*32 + i*16 + (l&15)),
    // k = s*KCHUNK + (l>>4)*8 + [0..7]  (+ kk*BK per step)
    const float* aptr0 = A + (size_t)(m0 + wm * 32 + (lane & 15)) * Nn
                           + (size_t)s * KCHUNK + (lane >> 4) * 8;
    const float* aptr1 = aptr0 + (size_t)16 * Nn;

    const int wbase = (t & 192) * 8;     // wave-uniform LDS ushort base for glds

    floatx4 acc[2][4];
#pragma unroll
    for (int i = 0; i < 2; ++i)
#pragma unroll
        for (int j = 0; j < 4; ++j) acc[i][j] = (floatx4)0.0f;

    // ---- prologue: stage B(0) into buf0, prefetch A(0) into regs
    {
        const size_t bb = ((size_t)c0 * 16 + bx * 8) * 512;
#ifdef HAS_GLDS
        GLDS16(Bhi + bb + t * 8,        &Bh[wbase]);
        GLDS16(Bhi + bb + 2048 + t * 8, &Bh[2048 + wbase]);
        GLDS16(Blo + bb + t * 8,        &Bl[wbase]);
        GLDS16(Blo + bb + 2048 + t * 8, &Bl[2048 + wbase]);
#else
        *(uint4*)&Bh[t * 8]        = *(const uint4*)(Bhi + bb + t * 8);
        *(uint4*)&Bh[2048 + t * 8] = *(const uint4*)(Bhi + bb + 2048 + t * 8);
        *(uint4*)&Bl[t * 8]        = *(const uint4*)(Blo + bb + t * 8);
        *(uint4*)&Bl[2048 + t * 8] = *(const uint4*)(Blo + bb + 2048 + t * 8);
#endif
        SCHED_FENCE();   // pin glds before the A loads (vmcnt ordering)
    }
    float4 pa0 = *(const float4*)(aptr0);
    float4 pa1 = *(const float4*)(aptr0 + 4);
    float4 pa2 = *(const float4*)(aptr1);
    float4 pa3 = *(const float4*)(aptr1 + 4);
    TILE_BARRIER();

#pragma unroll 2
    for (int kk = 0; kk < NIT - 1; ++kk) {
        const int p = kk & 1;
        // 1. stage B(kk+1) into the other buffer (issued first -> oldest vmcnt)
        {
            const size_t bb = ((size_t)(c0 + kk + 1) * 16 + bx * 8) * 512;
            const int db = (p ^ 1) * 4096 + wbase;
#ifdef HAS_GLDS
            GLDS16(Bhi + bb + t * 8,        &Bh[db]);
            GLDS16(Bhi + bb + 2048 + t * 8, &Bh[db + 2048]);
            GLDS16(Blo + bb + t * 8,        &Bl[db]);
            GLDS16(Blo + bb + 2048 + t * 8, &Bl[db + 2048]);
#else
            const int ds = (p ^ 1) * 4096;
            *(uint4*)&Bh[ds + t * 8]        = *(const uint4*)(Bhi + bb + t * 8);
            *(uint4*)&Bh[ds + 2048 + t * 8] = *(const uint4*)(Bhi + bb + 2048 + t * 8);
            *(uint4*)&Bl[ds + t * 8]        = *(const uint4*)(Blo + bb + t * 8);
            *(uint4*)&Bl[ds + 2048 + t * 8] = *(const uint4*)(Blo + bb + 2048 + t * 8);
#endif
            SCHED_FENCE();   // keep the 4 glds older than the 4 A loads below
        }
        // 2. issue next A loads early (latency hides under split+reads+MFMA)
        float4 na0 = *(const float4*)(aptr0 + (kk + 1) * BK);
        float4 na1 = *(const float4*)(aptr0 + (kk + 1) * BK + 4);
        float4 na2 = *(const float4*)(aptr1 + (kk + 1) * BK);
        float4 na3 = *(const float4*)(aptr1 + (kk + 1) * BK + 4);
        // 3. split current A registers into bf16 hi/lo fragments
        bf16x8 ah[2], al[2];
        split_frag(pa0, pa1, ah[0], al[0]);
        split_frag(pa2, pa3, ah[1], al[1]);
        pa0 = na0; pa1 = na1; pa2 = na2; pa3 = na3;
        // 4. read B fragments from current buffer
        bf16x8 fbh[4], fbl[4];
#pragma unroll
        for (int j = 0; j < 4; ++j) {
            fbh[j] = *(const bf16x8*)&Bh[p * 4096 + (wn * 4 + j) * 512 + lane * 8];
            fbl[j] = *(const bf16x8*)&Bl[p * 4096 + (wn * 4 + j) * 512 + lane * 8];
        }
        // 5. 3-pass MFMA (hh + hl + lh)
#pragma unroll
        for (int i = 0; i < 2; ++i)
#pragma unroll
            for (int j = 0; j < 4; ++j) {
                acc[i][j] = __builtin_amdgcn_mfma_f32_16x16x32_bf16(ah[i], fbh[j], acc[i][j], 0, 0, 0);
                acc[i][j] = __builtin_amdgcn_mfma_f32_16x16x32_bf16(ah[i], fbl[j], acc[i][j], 0, 0, 0);
                acc[i][j] = __builtin_amdgcn_mfma_f32_16x16x32_bf16(al[i], fbh[j], acc[i][j], 0, 0, 0);
            }
        TILE_BARRIER();
    }

    // ---- peeled last step (no prefetch, no barrier)
    {
        const int p = (NIT - 1) & 1;
        bf16x8 ah[2], al[2];
        split_frag(pa0, pa1, ah[0], al[0]);
        split_frag(pa2, pa3, ah[1], al[1]);
        bf16x8 fbh[4], fbl[4];
#pragma unroll
        for (int j = 0; j < 4; ++j) {
            fbh[j] = *(const bf16x8*)&Bh[p * 4096 + (wn * 4 + j) * 512 + lane * 8];
            fbl[j] = *(const bf16x8*)&Bl[p * 4096 + (wn * 4 + j) * 512 + lane * 8];
        }
#pragma unroll
        for (int i = 0; i < 2; ++i)
#pragma unroll
            for (int j = 0; j < 4; ++j) {
                acc[i][j] = __builtin_amdgcn_mfma_f32_16x16x32_bf16(ah[i], fbh[j], acc[i][j], 0, 0, 0);
                acc[i][j] = __builtin_amdgcn_mfma_f32_16x16x32_bf16(ah[i], fbl[j], acc[i][j], 0, 0, 0);
                acc[i][j] = __builtin_amdgcn_mfma_f32_16x16x32_bf16(al[i], fbh[j], acc[i][j], 0, 0, 0);
            }
    }

    // ---- epilogue
    const int row4 = (lane >> 4) * 4;
    const int col  = lane & 15;
    float* base = part + (size_t)s * PART_STRIDE;
#pragma unroll
    for (int i = 0; i < 2; ++i)
#pragma unroll
        for (int j = 0; j < 4; ++j) {
            const int n = bx * 128 + wn * 64 + j * 16 + col;
#pragma unroll
            for (int q = 0; q < 4; ++q) {
                const int m = m0 + wm * 32 + i * 16 + row4 + q;
                base[(size_t)m * HIDW + n] = acc[i][j][q];
            }
        }
}

// ---------------------------------------------------------------------------
// K2: one block per row — reduce KSPLIT partials, relu, dot w2 -> scores[row]
// (b2 omitted: constant shift doesn't change ordering)
// ---------------------------------------------------------------------------
__global__ __launch_bounds__(256) void score_rows(const float* __restrict__ part,
                                                  const float* __restrict__ b1,
                                                  const float* __restrict__ w2,
                                                  float* __restrict__ scores) {
    const int r = blockIdx.x;
    const int t = threadIdx.x;
    const size_t off = (size_t)r * HIDW + t;
    float h = 0.0f;
#pragma unroll
    for (int s = 0; s < KSPLIT; ++s) h += part[(size_t)s * PART_STRIDE + off];
    float p = fmaxf(h + b1[t], 0.0f) * w2[t];
#pragma unroll
    for (int o = 32; o > 0; o >>= 1) p += __shfl_down(p, o, 64);
    __shared__ float red[4];
    if ((t & 63) == 0) red[t >> 6] = p;
    __syncthreads();
    if (t == 0) scores[r] = red[0] + red[1] + red[2] + red[3];
}

// ---------------------------------------------------------------------------
// K3: one thread per batch — top-3 of 7, write index floats + sidx
// ---------------------------------------------------------------------------
__global__ __launch_bounds__(256) void topk_kernel(const float* __restrict__ scores,
                                                   float* __restrict__ out,
                                                   int* __restrict__ sidx) {
    const int b = threadIdx.x;
    float sc[Cc];
#pragma unroll
    for (int c = 0; c < Cc; ++c) sc[c] = scores[b * Cc + c];
    bool used[Cc] = {};
#pragma unroll
    for (int k = 0; k < SEL; ++k) {
        int best = 0;
        float bv = -3.4e38f;
#pragma unroll
        for (int c = 0; c < Cc; ++c)
            if (!used[c] && sc[c] > bv) { bv = sc[c]; best = c; }
        used[best] = true;
        sidx[b * SEL + k] = best;
        out[(size_t)Bn * SEL * Nn + b * SEL + k] = (float)best;
    }
}

// ---------------------------------------------------------------------------
// K4: gather — one block per (batch, sel)
// ---------------------------------------------------------------------------
__global__ __launch_bounds__(256) void gather_bands(const float* __restrict__ x,
                                                    const int* __restrict__ sidx,
                                                    float* __restrict__ out) {
    const int id = blockIdx.x;
    const int b  = id / SEL;
    const int band = sidx[id];
    const float4* src = (const float4*)(x + (size_t)(b * Cc + band) * Nn);
    float4* dst = (float4*)(out + (size_t)id * Nn);
    for (int i = threadIdx.x; i < Nn / 4; i += 256) dst[i] = src[i];
}

// ---------------------------------------------------------------------------
extern "C" void kernel_launch(void* const* d_in, const int* in_sizes, int n_in,
                              void* d_out, int out_size, void* d_ws, size_t ws_size,
                              hipStream_t stream) {
    const float* x  = (const float*)d_in[0];
    // d_in[1]=w_qkv, d_in[2]=b_qkv: dead in the reference forward
    const float* w1 = (const float*)d_in[3];
    const float* b1 = (const float*)d_in[4];
    const float* w2 = (const float*)d_in[5];
    const float* b2 = (const float*)d_in[6];
    (void)b2;
    float* out = (float*)d_out;

    char* ws = (char*)d_ws;
    float* part = (float*)ws;                                            // 29.36 MB
    unsigned short* bhi = (unsigned short*)(ws + KSPLIT * PART_STRIDE * sizeof(float));
    unsigned short* blo = bhi + (size_t)Nn * HIDW;                       // 8 MB each
    int*   sidx   = (int*)(blo + (size_t)Nn * HIDW);
    float* scores = (float*)(sidx + Bn * SEL);

    convert_w1<<<(Nn / 32) * 16 * 64 / 256, 256, 0, stream>>>(w1, bhi, blo);
    gemm_mfma<<<(HIDW / 128) * (Mrows / 64) * KSPLIT, 256, 0, stream>>>(x, bhi, blo, part);
    score_rows<<<Mrows, 256, 0, stream>>>(part, b1, w2, scores);
    topk_kernel<<<1, 256, 0, stream>>>(scores, out, sidx);
    gather_bands<<<Bn * SEL, 256, 0, stream>>>(x, sidx, out);
}

// Round 3
// 269.380 us; speedup vs baseline: 1.0892x; 1.0892x over previous
//
#include <hip/hip_runtime.h>

#define Bn    256
#define Cc    7
#define Nn    16384
#define HIDW  256
#define SEL   3
#define Mrows (Bn * Cc)            // 1792
#define BK    32
#define PART_STRIDE ((size_t)Mrows * HIDW)

typedef __attribute__((ext_vector_type(8))) short bf16x8;
typedef __attribute__((ext_vector_type(4))) float floatx4;

#if __has_builtin(__builtin_amdgcn_global_load_lds)
#define HAS_GLDS 1
#endif

// pack high-16 bits of two fp32 words: low ushort = ua>>16, high = ub>>16
__device__ __forceinline__ unsigned pack_hi16(unsigned ua, unsigned ub) {
#if __has_builtin(__builtin_amdgcn_perm)
    return __builtin_amdgcn_perm(ub, ua, 0x07060302u);
#else
    return (ua >> 16) | (ub & 0xffff0000u);
#endif
}

// truncation hi/lo split of a pair of floats -> packed hi word + packed lo word
__device__ __forceinline__ void split2(float a, float b, unsigned& hp, unsigned& lp) {
    unsigned ua = __float_as_uint(a), ub = __float_as_uint(b);
    float fa = __uint_as_float(ua & 0xffff0000u);
    float fb = __uint_as_float(ub & 0xffff0000u);
    float la = a - fa, lb = b - fb;            // exact residuals
    hp = pack_hi16(ua, ub);
    lp = pack_hi16(__float_as_uint(la), __float_as_uint(lb));
}

// ---------------------------------------------------------------------------
// K0: w1[k][n] fp32 -> fragment-ordered bf16 hi/lo planes (trunc split).
// chunk(c,T,lane) holds B[k=c*32+(lane>>4)*8+j][n=T*16+(lane&15)], j=0..7,
// at ushort offset ((c*16+T)*64+lane)*8.   (unchanged from round-0)
// ---------------------------------------------------------------------------
__global__ __launch_bounds__(256) void convert_w1(const float* __restrict__ w1,
                                                  unsigned short* __restrict__ bhi,
                                                  unsigned short* __restrict__ blo) {
    const int id = blockIdx.x * 256 + threadIdx.x;
    const int l  = id & 63;
    const int ct = id >> 6;
    const int T  = ct & 15;
    const int c  = ct >> 4;
    const int n  = T * 16 + (l & 15);
    const int k  = c * 32 + (l >> 4) * 8;
    float f[8];
#pragma unroll
    for (int j = 0; j < 8; ++j) f[j] = w1[(size_t)(k + j) * HIDW + n];
    unsigned hp[4], lp[4];
#pragma unroll
    for (int m = 0; m < 4; ++m) split2(f[2 * m], f[2 * m + 1], hp[m], lp[m]);
    *(uint4*)(bhi + (size_t)id * 8) = make_uint4(hp[0], hp[1], hp[2], hp[3]);
    *(uint4*)(blo + (size_t)id * 8) = make_uint4(lp[0], lp[1], lp[2], lp[3]);
}

// ---------------------------------------------------------------------------
// K1: MFMA GEMM  part[s][M][256] = feat[M][Kslice] @ w1[Kslice][256]
//     128x128 tile, 4 waves 2x2, 16x16x32 bf16, 3-pass trunc hi/lo split.
//     B staged via global_load_lds (fragment-ordered in global).
//     ROUND-0 STRUCTURE UNCHANGED; kchunk is now a runtime arg so the host
//     can pick KSPLIT=32 (grid 896 blocks, 3.5/CU) when workspace allows.
// ---------------------------------------------------------------------------
__global__ __launch_bounds__(256) void gemm_mfma(const float* __restrict__ A,
                                                 const unsigned short* __restrict__ Bhi,
                                                 const unsigned short* __restrict__ Blo,
                                                 float* __restrict__ part,
                                                 int kchunk) {
    __shared__ unsigned short Ah[4096], Al[4096], Bh[4096], Bl[4096];

    const int bx = blockIdx.x;
    const int m0 = blockIdx.y * 128;
    const int s  = blockIdx.z;
    const int k0 = s * kchunk;
    const int t  = threadIdx.x;
    const int lane = t & 63;
    const int w    = t >> 6;
    const int wm   = w & 1;
    const int wn   = w >> 1;

    const int ar  = t >> 1;
    const int kof = (t & 1) * 16;
    const float* aptr = A + (size_t)(m0 + ar) * Nn + k0 + kof;
    const int aidx0 = (ar >> 4) * 512 + ((ar & 15) + ((kof >> 3) + 0) * 16) * 8;
    const int aidx1 = (ar >> 4) * 512 + ((ar & 15) + ((kof >> 3) + 1) * 16) * 8;
    const int wbase = (t & 192) * 8;   // wave-uniform LDS ushort base for glds

    floatx4 acc[4][4];
#pragma unroll
    for (int i = 0; i < 4; ++i)
#pragma unroll
        for (int j = 0; j < 4; ++j) acc[i][j] = (floatx4)0.0f;

    for (int kk = 0; kk < kchunk; kk += BK) {
        float4 a0 = *(const float4*)(aptr + kk + 0);
        float4 a1 = *(const float4*)(aptr + kk + 4);
        float4 a2 = *(const float4*)(aptr + kk + 8);
        float4 a3 = *(const float4*)(aptr + kk + 12);
        const size_t bbase = ((size_t)(((k0 + kk) >> 5) * 16 + bx * 8)) * 512;

#ifndef HAS_GLDS
        uint4 bh0 = *(const uint4*)(Bhi + bbase + t * 8);
        uint4 bh1 = *(const uint4*)(Bhi + bbase + 2048 + t * 8);
        uint4 bl0 = *(const uint4*)(Blo + bbase + t * 8);
        uint4 bl1 = *(const uint4*)(Blo + bbase + 2048 + t * 8);
#endif
        // trunc hi/lo split of 16 A elements (reg-only, overlaps loads)
        float af[16] = {a0.x, a0.y, a0.z, a0.w, a1.x, a1.y, a1.z, a1.w,
                        a2.x, a2.y, a2.z, a2.w, a3.x, a3.y, a3.z, a3.w};
        unsigned hp[8], lp[8];
#pragma unroll
        for (int m = 0; m < 8; ++m) split2(af[2 * m], af[2 * m + 1], hp[m], lp[m]);

        __syncthreads();   // previous iteration's frag reads complete
#ifdef HAS_GLDS
        __builtin_amdgcn_global_load_lds(
            (const __attribute__((address_space(1))) void*)(Bhi + bbase + t * 8),
            (__attribute__((address_space(3))) void*)&Bh[wbase], 16, 0, 0);
        __builtin_amdgcn_global_load_lds(
            (const __attribute__((address_space(1))) void*)(Bhi + bbase + 2048 + t * 8),
            (__attribute__((address_space(3))) void*)&Bh[2048 + wbase], 16, 0, 0);
        __builtin_amdgcn_global_load_lds(
            (const __attribute__((address_space(1))) void*)(Blo + bbase + t * 8),
            (__attribute__((address_space(3))) void*)&Bl[wbase], 16, 0, 0);
        __builtin_amdgcn_global_load_lds(
            (const __attribute__((address_space(1))) void*)(Blo + bbase + 2048 + t * 8),
            (__attribute__((address_space(3))) void*)&Bl[2048 + wbase], 16, 0, 0);
#else
        *(uint4*)&Bh[t * 8]        = bh0;
        *(uint4*)&Bh[2048 + t * 8] = bh1;
        *(uint4*)&Bl[t * 8]        = bl0;
        *(uint4*)&Bl[2048 + t * 8] = bl1;
#endif
        *(uint4*)&Ah[aidx0] = make_uint4(hp[0], hp[1], hp[2], hp[3]);
        *(uint4*)&Ah[aidx1] = make_uint4(hp[4], hp[5], hp[6], hp[7]);
        *(uint4*)&Al[aidx0] = make_uint4(lp[0], lp[1], lp[2], lp[3]);
        *(uint4*)&Al[aidx1] = make_uint4(lp[4], lp[5], lp[6], lp[7]);
        __syncthreads();

        bf16x8 fah[4], fal[4], fbh[4], fbl[4];
#pragma unroll
        for (int i = 0; i < 4; ++i) {
            fah[i] = *(const bf16x8*)&Ah[(wm * 4 + i) * 512 + lane * 8];
            fal[i] = *(const bf16x8*)&Al[(wm * 4 + i) * 512 + lane * 8];
        }
#pragma unroll
        for (int j = 0; j < 4; ++j) {
            fbh[j] = *(const bf16x8*)&Bh[(wn * 4 + j) * 512 + lane * 8];
            fbl[j] = *(const bf16x8*)&Bl[(wn * 4 + j) * 512 + lane * 8];
        }
#pragma unroll
        for (int i = 0; i < 4; ++i)
#pragma unroll
            for (int j = 0; j < 4; ++j) {
                acc[i][j] = __builtin_amdgcn_mfma_f32_16x16x32_bf16(fah[i], fbh[j], acc[i][j], 0, 0, 0);
                acc[i][j] = __builtin_amdgcn_mfma_f32_16x16x32_bf16(fah[i], fbl[j], acc[i][j], 0, 0, 0);
                acc[i][j] = __builtin_amdgcn_mfma_f32_16x16x32_bf16(fal[i], fbh[j], acc[i][j], 0, 0, 0);
            }
    }

    const int row4 = (lane >> 4) * 4;
    const int col  = lane & 15;
    float* base = part + (size_t)s * PART_STRIDE;
#pragma unroll
    for (int i = 0; i < 4; ++i)
#pragma unroll
        for (int j = 0; j < 4; ++j) {
            const int n = bx * 128 + wn * 64 + j * 16 + col;
#pragma unroll
            for (int p = 0; p < 4; ++p) {
                const int m = m0 + wm * 64 + i * 16 + row4 + p;
                base[(size_t)m * HIDW + n] = acc[i][j][p];
            }
        }
}

// ---------------------------------------------------------------------------
// K2: one block per row — reduce ksplit partials, relu, dot w2 -> scores[row]
// (b2 omitted: constant shift doesn't change ordering)
// ---------------------------------------------------------------------------
__global__ __launch_bounds__(256) void score_rows(const float* __restrict__ part,
                                                  const float* __restrict__ b1,
                                                  const float* __restrict__ w2,
                                                  float* __restrict__ scores,
                                                  int ksplit) {
    const int r = blockIdx.x;
    const int t = threadIdx.x;
    const size_t off = (size_t)r * HIDW + t;
    float h = 0.0f;
#pragma unroll 8
    for (int s = 0; s < ksplit; ++s) h += part[(size_t)s * PART_STRIDE + off];
    float p = fmaxf(h + b1[t], 0.0f) * w2[t];
#pragma unroll
    for (int o = 32; o > 0; o >>= 1) p += __shfl_down(p, o, 64);
    __shared__ float red[4];
    if ((t & 63) == 0) red[t >> 6] = p;
    __syncthreads();
    if (t == 0) scores[r] = red[0] + red[1] + red[2] + red[3];
}

// ---------------------------------------------------------------------------
// K3: gather + inline top-k — one block per (batch, sel).
// Each block redundantly computes the top-3 of its batch's 7 scores
// (deterministic: identical float compares -> identical picks across blocks),
// copies its band, and thread 0 writes the index output. Replaces the old
// single-block topk kernel (a whole-GPU serialization point) + sidx buffer.
// ---------------------------------------------------------------------------
__global__ __launch_bounds__(256) void gather_bands(const float* __restrict__ x,
                                                    const float* __restrict__ scores,
                                                    float* __restrict__ out) {
    const int id = blockIdx.x;
    const int b  = id / SEL;
    const int kk = id - b * SEL;          // which of the top-3 this block copies
    float sc[Cc];
#pragma unroll
    for (int c = 0; c < Cc; ++c) sc[c] = scores[b * Cc + c];
    bool used[Cc] = {};
    int band = 0;
#pragma unroll
    for (int k = 0; k <= SEL - 1; ++k) {
        int best = 0;
        float bv = -3.4e38f;
#pragma unroll
        for (int c = 0; c < Cc; ++c)
            if (!used[c] && sc[c] > bv) { bv = sc[c]; best = c; }
        used[best] = true;
        if (k == kk) band = best;
        if (k > kk) break;
    }
    if (threadIdx.x == 0)
        out[(size_t)Bn * SEL * Nn + b * SEL + kk] = (float)band;
    const float4* src = (const float4*)(x + (size_t)(b * Cc + band) * Nn);
    float4* dst = (float4*)(out + (size_t)id * Nn);
    for (int i = threadIdx.x; i < Nn / 4; i += 256) dst[i] = src[i];
}

// ---------------------------------------------------------------------------
extern "C" void kernel_launch(void* const* d_in, const int* in_sizes, int n_in,
                              void* d_out, int out_size, void* d_ws, size_t ws_size,
                              hipStream_t stream) {
    const float* x  = (const float*)d_in[0];
    // d_in[1]=w_qkv, d_in[2]=b_qkv: dead in the reference forward
    const float* w1 = (const float*)d_in[3];
    const float* b1 = (const float*)d_in[4];
    const float* w2 = (const float*)d_in[5];
    const float* b2 = (const float*)d_in[6];
    (void)b2;
    float* out = (float*)d_out;

    // KSPLIT=32 -> 896 gemm blocks (3.5/CU) if the workspace can hold the
    // 58.7 MB partial buffer; otherwise fall back to the round-0 KSPLIT=16.
    const size_t bplane = (size_t)Nn * HIDW;                  // ushorts per plane
    const size_t need32 = 32 * PART_STRIDE * sizeof(float) + 2 * bplane * sizeof(unsigned short)
                        + (size_t)Mrows * sizeof(float) + 4096;
    const int ksplit = (ws_size >= need32) ? 32 : 16;
    const int kchunk = Nn / ksplit;

    char* ws = (char*)d_ws;
    float* part = (float*)ws;
    unsigned short* bhi = (unsigned short*)(ws + (size_t)ksplit * PART_STRIDE * sizeof(float));
    unsigned short* blo = bhi + bplane;
    float* scores = (float*)(blo + bplane);

    convert_w1<<<(Nn / 32) * 16 * 64 / 256, 256, 0, stream>>>(w1, bhi, blo);
    gemm_mfma<<<dim3(HIDW / 128, Mrows / 128, ksplit), 256, 0, stream>>>(x, bhi, blo, part, kchunk);
    score_rows<<<Mrows, 256, 0, stream>>>(part, b1, w2, scores, ksplit);
    gather_bands<<<Bn * SEL, 256, 0, stream>>>(x, scores, out);
}

// Round 4
// 256.274 us; speedup vs baseline: 1.1449x; 1.0511x over previous
//
#include <hip/hip_runtime.h>

#define Bn    256
#define Cc    7
#define Nn    16384
#define HIDW  256
#define SEL   3
#define Mrows (Bn * Cc)            // 1792
#define KSPLIT 16
#define KCHUNK (Nn / KSPLIT)       // 1024
#define BK    32
#define PART_STRIDE ((size_t)Mrows * HIDW)

typedef __attribute__((ext_vector_type(8))) short bf16x8;
typedef __attribute__((ext_vector_type(4))) float floatx4;

#if __has_builtin(__builtin_amdgcn_global_load_lds)
#define HAS_GLDS 1
#endif

#if __has_builtin(__builtin_amdgcn_sched_barrier)
#define SCHED_FENCE() __builtin_amdgcn_sched_barrier(0)
#else
#define SCHED_FENCE()
#endif

// pack high-16 bits of two fp32 words: low ushort = ua>>16, high = ub>>16
__device__ __forceinline__ unsigned pack_hi16(unsigned ua, unsigned ub) {
#if __has_builtin(__builtin_amdgcn_perm)
    return __builtin_amdgcn_perm(ub, ua, 0x07060302u);
#else
    return (ua >> 16) | (ub & 0xffff0000u);
#endif
}

// truncation hi/lo split of a pair of floats -> packed hi word + packed lo word
__device__ __forceinline__ void split2(float a, float b, unsigned& hp, unsigned& lp) {
    unsigned ua = __float_as_uint(a), ub = __float_as_uint(b);
    float fa = __uint_as_float(ua & 0xffff0000u);
    float fb = __uint_as_float(ub & 0xffff0000u);
    float la = a - fa, lb = b - fb;            // exact residuals
    hp = pack_hi16(ua, ub);
    lp = pack_hi16(__float_as_uint(la), __float_as_uint(lb));
}

// ---------------------------------------------------------------------------
// K0: w1[k][n] fp32 -> fragment-ordered bf16 hi/lo planes (trunc split).
// chunk(c,T,lane) holds B[k=c*32+(lane>>4)*8+j][n=T*16+(lane&15)], j=0..7,
// at ushort offset ((c*16+T)*64+lane)*8.   (unchanged from round-0)
// ---------------------------------------------------------------------------
__global__ __launch_bounds__(256) void convert_w1(const float* __restrict__ w1,
                                                  unsigned short* __restrict__ bhi,
                                                  unsigned short* __restrict__ blo) {
    const int id = blockIdx.x * 256 + threadIdx.x;
    const int l  = id & 63;
    const int ct = id >> 6;
    const int T  = ct & 15;
    const int c  = ct >> 4;
    const int n  = T * 16 + (l & 15);
    const int k  = c * 32 + (l >> 4) * 8;
    float f[8];
#pragma unroll
    for (int j = 0; j < 8; ++j) f[j] = w1[(size_t)(k + j) * HIDW + n];
    unsigned hp[4], lp[4];
#pragma unroll
    for (int m = 0; m < 4; ++m) split2(f[2 * m], f[2 * m + 1], hp[m], lp[m]);
    *(uint4*)(bhi + (size_t)id * 8) = make_uint4(hp[0], hp[1], hp[2], hp[3]);
    *(uint4*)(blo + (size_t)id * 8) = make_uint4(lp[0], lp[1], lp[2], lp[3]);
}

// ---------------------------------------------------------------------------
// K1: MFMA GEMM  part[s][M][256] = feat[M][Kslice] @ w1[Kslice][256]
//   128x128 tile, 4 waves 2x2, 16x16x32 bf16, 3-pass trunc hi/lo split.
//   ROUND-0 structure and arithmetic, with counted-vmcnt barrier mechanics:
//   - barrier#1 is a raw s_barrier (no vmcnt(0) drain: __syncthreads would
//     drain the in-flight A prefetch and expose its full HBM latency)
//   - A(kk+BK) register loads are issued in the staging phase AFTER the 4
//     global_load_lds (order pinned by sched_barrier), consumed next iter
//   - barrier#2 waits vmcnt(4) lgkmcnt(0): retires exactly the 4 oldest vmem
//     (the glds, in-order retire) + the A ds_writes; A prefetch stays in
//     flight across the barrier under the 48 MFMAs.
//   Invariant: every iteration issues exactly 4 glds then 4 A loads (the last
//   iteration issues clamped dummy A loads) so vmcnt(4) is always correct.
// ---------------------------------------------------------------------------
__global__ __launch_bounds__(256) void gemm_mfma(const float* __restrict__ A,
                                                 const unsigned short* __restrict__ Bhi,
                                                 const unsigned short* __restrict__ Blo,
                                                 float* __restrict__ part) {
    __shared__ unsigned short Ah[4096], Al[4096], Bh[4096], Bl[4096];

    const int bx = blockIdx.x;
    const int m0 = blockIdx.y * 128;
    const int s  = blockIdx.z;
    const int k0 = s * KCHUNK;
    const int t  = threadIdx.x;
    const int lane = t & 63;
    const int w    = t >> 6;
    const int wm   = w & 1;
    const int wn   = w >> 1;

    const int ar  = t >> 1;
    const int kof = (t & 1) * 16;
    const float* aptr = A + (size_t)(m0 + ar) * Nn + k0 + kof;
    const int aidx0 = (ar >> 4) * 512 + ((ar & 15) + ((kof >> 3) + 0) * 16) * 8;
    const int aidx1 = (ar >> 4) * 512 + ((ar & 15) + ((kof >> 3) + 1) * 16) * 8;
    const int wbase = (t & 192) * 8;   // wave-uniform LDS ushort base for glds

    floatx4 acc[4][4];
#pragma unroll
    for (int i = 0; i < 4; ++i)
#pragma unroll
        for (int j = 0; j < 4; ++j) acc[i][j] = (floatx4)0.0f;

    // prologue: A(0) register prefetch (waited at first split)
    float4 pa0 = *(const float4*)(aptr + 0);
    float4 pa1 = *(const float4*)(aptr + 4);
    float4 pa2 = *(const float4*)(aptr + 8);
    float4 pa3 = *(const float4*)(aptr + 12);

    for (int kk = 0; kk < KCHUNK; kk += BK) {
        // ---- split phase (reg-only; compiler inserts the vmcnt wait for pa)
        float af[16] = {pa0.x, pa0.y, pa0.z, pa0.w, pa1.x, pa1.y, pa1.z, pa1.w,
                        pa2.x, pa2.y, pa2.z, pa2.w, pa3.x, pa3.y, pa3.z, pa3.w};
        unsigned hp[8], lp[8];
#pragma unroll
        for (int m = 0; m < 8; ++m) split2(af[2 * m], af[2 * m + 1], hp[m], lp[m]);

        // ---- barrier #1: raw (previous frag reads are retired; no vmem drain)
        SCHED_FENCE();
        __builtin_amdgcn_s_barrier();
        SCHED_FENCE();

        // ---- staging: 4 glds first (oldest vmem ops of this iteration)
        const size_t bbase = ((size_t)(((k0 + kk) >> 5) * 16 + bx * 8)) * 512;
#ifdef HAS_GLDS
        __builtin_amdgcn_global_load_lds(
            (const __attribute__((address_space(1))) void*)(Bhi + bbase + t * 8),
            (__attribute__((address_space(3))) void*)&Bh[wbase], 16, 0, 0);
        __builtin_amdgcn_global_load_lds(
            (const __attribute__((address_space(1))) void*)(Bhi + bbase + 2048 + t * 8),
            (__attribute__((address_space(3))) void*)&Bh[2048 + wbase], 16, 0, 0);
        __builtin_amdgcn_global_load_lds(
            (const __attribute__((address_space(1))) void*)(Blo + bbase + t * 8),
            (__attribute__((address_space(3))) void*)&Bl[wbase], 16, 0, 0);
        __builtin_amdgcn_global_load_lds(
            (const __attribute__((address_space(1))) void*)(Blo + bbase + 2048 + t * 8),
            (__attribute__((address_space(3))) void*)&Bl[2048 + wbase], 16, 0, 0);
#else
        *(uint4*)&Bh[t * 8]        = *(const uint4*)(Bhi + bbase + t * 8);
        *(uint4*)&Bh[2048 + t * 8] = *(const uint4*)(Bhi + bbase + 2048 + t * 8);
        *(uint4*)&Bl[t * 8]        = *(const uint4*)(Blo + bbase + t * 8);
        *(uint4*)&Bl[2048 + t * 8] = *(const uint4*)(Blo + bbase + 2048 + t * 8);
#endif
        SCHED_FENCE();   // glds pinned oldest: nothing below may move above

        // ---- A ds_writes (lgkm) + A(kk+BK) register prefetch (younger vmem)
        *(uint4*)&Ah[aidx0] = make_uint4(hp[0], hp[1], hp[2], hp[3]);
        *(uint4*)&Ah[aidx1] = make_uint4(hp[4], hp[5], hp[6], hp[7]);
        *(uint4*)&Al[aidx0] = make_uint4(lp[0], lp[1], lp[2], lp[3]);
        *(uint4*)&Al[aidx1] = make_uint4(lp[4], lp[5], lp[6], lp[7]);
        const int kn = (kk + BK < KCHUNK) ? (kk + BK) : kk;  // clamp keeps count
        pa0 = *(const float4*)(aptr + kn + 0);
        pa1 = *(const float4*)(aptr + kn + 4);
        pa2 = *(const float4*)(aptr + kn + 8);
        pa3 = *(const float4*)(aptr + kn + 12);

        // ---- barrier #2: retire the 4 glds + ds_writes; A loads stay in flight
        SCHED_FENCE();
#ifdef HAS_GLDS
        asm volatile("s_waitcnt vmcnt(4) lgkmcnt(0)" ::: "memory");
#else
        asm volatile("s_waitcnt vmcnt(4) lgkmcnt(0)" ::: "memory");
#endif
        __builtin_amdgcn_s_barrier();
        SCHED_FENCE();

        // ---- fragment reads + 48 MFMA (lgkm waits auto-inserted)
        bf16x8 fah[4], fal[4], fbh[4], fbl[4];
#pragma unroll
        for (int i = 0; i < 4; ++i) {
            fah[i] = *(const bf16x8*)&Ah[(wm * 4 + i) * 512 + lane * 8];
            fal[i] = *(const bf16x8*)&Al[(wm * 4 + i) * 512 + lane * 8];
        }
#pragma unroll
        for (int j = 0; j < 4; ++j) {
            fbh[j] = *(const bf16x8*)&Bh[(wn * 4 + j) * 512 + lane * 8];
            fbl[j] = *(const bf16x8*)&Bl[(wn * 4 + j) * 512 + lane * 8];
        }
#pragma unroll
        for (int i = 0; i < 4; ++i)
#pragma unroll
            for (int j = 0; j < 4; ++j) {
                acc[i][j] = __builtin_amdgcn_mfma_f32_16x16x32_bf16(fah[i], fbh[j], acc[i][j], 0, 0, 0);
                acc[i][j] = __builtin_amdgcn_mfma_f32_16x16x32_bf16(fah[i], fbl[j], acc[i][j], 0, 0, 0);
                acc[i][j] = __builtin_amdgcn_mfma_f32_16x16x32_bf16(fal[i], fbh[j], acc[i][j], 0, 0, 0);
            }
    }

    const int row4 = (lane >> 4) * 4;
    const int col  = lane & 15;
    float* base = part + (size_t)s * PART_STRIDE;
#pragma unroll
    for (int i = 0; i < 4; ++i)
#pragma unroll
        for (int j = 0; j < 4; ++j) {
            const int n = bx * 128 + wn * 64 + j * 16 + col;
#pragma unroll
            for (int p = 0; p < 4; ++p) {
                const int m = m0 + wm * 64 + i * 16 + row4 + p;
                base[(size_t)m * HIDW + n] = acc[i][j][p];
            }
        }
}

// ---------------------------------------------------------------------------
// K2: one block per row — reduce KSPLIT partials, relu, dot w2 -> scores[row]
// (b2 omitted: constant shift doesn't change ordering)
// ---------------------------------------------------------------------------
__global__ __launch_bounds__(256) void score_rows(const float* __restrict__ part,
                                                  const float* __restrict__ b1,
                                                  const float* __restrict__ w2,
                                                  float* __restrict__ scores) {
    const int r = blockIdx.x;
    const int t = threadIdx.x;
    const size_t off = (size_t)r * HIDW + t;
    float h = 0.0f;
#pragma unroll
    for (int s = 0; s < KSPLIT; ++s) h += part[(size_t)s * PART_STRIDE + off];
    float p = fmaxf(h + b1[t], 0.0f) * w2[t];
#pragma unroll
    for (int o = 32; o > 0; o >>= 1) p += __shfl_down(p, o, 64);
    __shared__ float red[4];
    if ((t & 63) == 0) red[t >> 6] = p;
    __syncthreads();
    if (t == 0) scores[r] = red[0] + red[1] + red[2] + red[3];
}

// ---------------------------------------------------------------------------
// K3: gather + inline top-k — one block per (batch, sel).
// Each block redundantly computes the top-3 of its batch's 7 scores
// (deterministic float compares -> identical picks across blocks), copies its
// band, thread 0 writes the index output.
// ---------------------------------------------------------------------------
__global__ __launch_bounds__(256) void gather_bands(const float* __restrict__ x,
                                                    const float* __restrict__ scores,
                                                    float* __restrict__ out) {
    const int id = blockIdx.x;
    const int b  = id / SEL;
    const int kk = id - b * SEL;          // which of the top-3 this block copies
    float sc[Cc];
#pragma unroll
    for (int c = 0; c < Cc; ++c) sc[c] = scores[b * Cc + c];
    bool used[Cc] = {};
    int band = 0;
#pragma unroll
    for (int k = 0; k <= SEL - 1; ++k) {
        int best = 0;
        float bv = -3.4e38f;
#pragma unroll
        for (int c = 0; c < Cc; ++c)
            if (!used[c] && sc[c] > bv) { bv = sc[c]; best = c; }
        used[best] = true;
        if (k == kk) band = best;
        if (k > kk) break;
    }
    if (threadIdx.x == 0)
        out[(size_t)Bn * SEL * Nn + b * SEL + kk] = (float)band;
    const float4* src = (const float4*)(x + (size_t)(b * Cc + band) * Nn);
    float4* dst = (float4*)(out + (size_t)id * Nn);
    for (int i = threadIdx.x; i < Nn / 4; i += 256) dst[i] = src[i];
}

// ---------------------------------------------------------------------------
extern "C" void kernel_launch(void* const* d_in, const int* in_sizes, int n_in,
                              void* d_out, int out_size, void* d_ws, size_t ws_size,
                              hipStream_t stream) {
    const float* x  = (const float*)d_in[0];
    // d_in[1]=w_qkv, d_in[2]=b_qkv: dead in the reference forward
    const float* w1 = (const float*)d_in[3];
    const float* b1 = (const float*)d_in[4];
    const float* w2 = (const float*)d_in[5];
    const float* b2 = (const float*)d_in[6];
    (void)b2;
    float* out = (float*)d_out;

    char* ws = (char*)d_ws;
    float* part = (float*)ws;                                            // 29.36 MB
    unsigned short* bhi = (unsigned short*)(ws + KSPLIT * PART_STRIDE * sizeof(float));
    unsigned short* blo = bhi + (size_t)Nn * HIDW;                       // 8 MB each
    float* scores = (float*)(blo + (size_t)Nn * HIDW);

    convert_w1<<<(Nn / 32) * 16 * 64 / 256, 256, 0, stream>>>(w1, bhi, blo);
    gemm_mfma<<<dim3(HIDW / 128, Mrows / 128, KSPLIT), 256, 0, stream>>>(x, bhi, blo, part);
    score_rows<<<Mrows, 256, 0, stream>>>(part, b1, w2, scores);
    gather_bands<<<Bn * SEL, 256, 0, stream>>>(x, scores, out);
}